// Round 9
// baseline (56.042 us; speedup 1.0000x reference)
//
#include <hip/hip_runtime.h>
#include <hip/hip_bf16.h>

#define B_N 2048
#define E_N 64
#define D_N 512
#define O_N 512
#define NSL 8     // k-slices
#define KS  64    // k per slice
#define WLD 514   // ws row stride in ushorts (odd/2 -> bank = k + c/2, 2-way free)

typedef __bf16 bf16x8 __attribute__((ext_vector_type(8)));
typedef float  f32x4  __attribute__((ext_vector_type(4)));

__device__ __forceinline__ unsigned cvt2(float a, float b) {
  union { __hip_bfloat162 h; unsigned u; } c;
  c.h = __float22bfloat162_rn(make_float2(a, b));
  return c.u;   // low 16 = a, high 16 = b
}

// 8 blocks x 256: global-atomic bucketing (output is order-invariant).
__global__ __launch_bounds__(256)
void bucket_kernel(const int* __restrict__ opt, int* __restrict__ cnt,
                   int* __restrict__ list) {
  int b = blockIdx.x * 256 + threadIdx.x;
  int e = opt[b];
  int slot = atomicAdd(&cnt[e], 1);
  list[e * B_N + slot] = b;
}

// out[b][:] = bias[opt[b]][:]  (k-slice partials atomically accumulate on top)
__global__ __launch_bounds__(256)
void bias_init_kernel(const int* __restrict__ opt, const float* __restrict__ bias,
                      float* __restrict__ out) {
  int gid = blockIdx.x * 256 + threadIdx.x;   // 1024 blocks
  int b  = gid >> 7;
  int o4 = gid & 127;
  int e  = opt[b];
  reinterpret_cast<float4*>(out)[(size_t)b * 128 + o4] =
      reinterpret_cast<const float4*>(bias)[(size_t)e * 128 + o4];
}

// Split-K grouped GEMM. Block = (expert e, 64-k slice s): W slice is a
// CONTIGUOUS 128 KB, staged two-phase (16 indep float4/thread -> regs -> bf16
// LDS, the R8-proven MLP pattern). 8 waves x 64 out-cols; B-frags in regs
// (read once); A-frags per-lane from global x; ONE barrier per block; fp32
// atomicAdd partials onto bias-initialized out (R7-verified path).
__global__ __launch_bounds__(512, 4)
void gemm_kernel(const float* __restrict__ x, const float* __restrict__ w,
                 const int* __restrict__ cnt, const int* __restrict__ list,
                 float* __restrict__ out) {
  __shared__ unsigned short ws[KS * WLD];   // 66 KB bf16 [k][c], pad-514

  const int e    = blockIdx.x;
  const int s    = blockIdx.y;
  const int t    = threadIdx.x;
  const int lane = t & 63;
  const int wave = t >> 6;
  const int n    = cnt[e];
  if (n == 0) return;

  const int m_in = lane & 15;
  const int g    = lane >> 4;
  const int* mylist = list + e * B_N;

  // ---- stage W slice: contiguous 128 KB fp32 -> bf16 LDS, two phases ----
  const float* wsl = w + (size_t)e * D_N * O_N + (size_t)s * KS * O_N;
  float4 f[16];
#pragma unroll
  for (int i = 0; i < 16; ++i)
    f[i] = *reinterpret_cast<const float4*>(wsl + (size_t)(t + i * 512) * 4);
#pragma unroll
  for (int i = 0; i < 16; ++i) {
    int idx = t + i * 512;
    int k   = idx >> 7;                  // 128 float4 per k-row
    int c4  = (idx & 127) * 4;
    unsigned short* wp = &ws[k * WLD + c4];
    *reinterpret_cast<unsigned*>(wp)     = cvt2(f[i].x, f[i].y);
    *reinterpret_cast<unsigned*>(wp + 2) = cvt2(f[i].z, f[i].w);
  }
  __syncthreads();     // the only barrier in this kernel

  // ---- this wave's 8 B-fragments -> registers (read once) ----
  union { unsigned short us[8]; bf16x8 v; } frag[4][2];
#pragma unroll
  for (int cf = 0; cf < 4; ++cf) {
    const int c = wave * 64 + cf * 16 + m_in;
#pragma unroll
    for (int ks = 0; ks < 2; ++ks)
#pragma unroll
      for (int j = 0; j < 8; ++j)
        frag[cf][ks].us[j] = ws[(ks * 32 + g * 8 + j) * WLD + c];
  }

  const float* xsl = x + (size_t)s * KS;   // this slice's k-columns of x

#pragma unroll 1
  for (int m0 = 0; m0 < n; m0 += 16) {
    // A-fragments: lane (m_in, g) holds x[row][k = ks*32 + g*8 .. +8]
    int sa = m0 + m_in;
    const float* xr = xsl + (size_t)mylist[sa < n ? sa : 0] * D_N + g * 8;
    union { float4 q[2]; float e8[8]; } xa, xb;
    xa.q[0] = *reinterpret_cast<const float4*>(xr);
    xa.q[1] = *reinterpret_cast<const float4*>(xr + 4);
    xb.q[0] = *reinterpret_cast<const float4*>(xr + 32);
    xb.q[1] = *reinterpret_cast<const float4*>(xr + 36);
    union { unsigned u[4]; bf16x8 v; } a0, a1;
#pragma unroll
    for (int p = 0; p < 4; ++p) {
      a0.u[p] = cvt2(xa.e8[2 * p], xa.e8[2 * p + 1]);
      a1.u[p] = cvt2(xb.e8[2 * p], xb.e8[2 * p + 1]);
    }

    f32x4 acc[4];
#pragma unroll
    for (int cf = 0; cf < 4; ++cf) {
      acc[cf] = (f32x4){0.f, 0.f, 0.f, 0.f};
      acc[cf] = __builtin_amdgcn_mfma_f32_16x16x32_bf16(a0.v, frag[cf][0].v, acc[cf], 0, 0, 0);
      acc[cf] = __builtin_amdgcn_mfma_f32_16x16x32_bf16(a1.v, frag[cf][1].v, acc[cf], 0, 0, 0);
    }

    // D layout (m89-verified): col = lane&15, row(sample slot) = g*4 + r
#pragma unroll
    for (int r = 0; r < 4; ++r) {
      int so = m0 + g * 4 + r;
      if (so < n) {
        float* orow = out + (size_t)mylist[so] * O_N + wave * 64 + m_in;
#pragma unroll
        for (int cf = 0; cf < 4; ++cf)
          atomicAdd(orow + cf * 16, acc[cf][r]);
      }
    }
  }
}

extern "C" void kernel_launch(void* const* d_in, const int* in_sizes, int n_in,
                              void* d_out, int out_size, void* d_ws, size_t ws_size,
                              hipStream_t stream) {
  const float* x      = (const float*)d_in[0];
  const int*   option = (const int*)d_in[1];
  const float* weight = (const float*)d_in[2];
  const float* bias   = (const float*)d_in[3];
  float* out = (float*)d_out;

  int* cnt  = (int*)d_ws;                    // 64 ints
  int* list = (int*)((char*)d_ws + 256);     // 64 * 2048 ints

  hipMemsetAsync(cnt, 0, E_N * sizeof(int), stream);
  bucket_kernel<<<B_N / 256, 256, 0, stream>>>(option, cnt, list);
  bias_init_kernel<<<(B_N * O_N / 4) / 256, 256, 0, stream>>>(option, bias, out);
  gemm_kernel<<<dim3(E_N, NSL), 512, 0, stream>>>(x, weight, cnt, list, out);
}

// Round 10
// 51.737 us; speedup vs baseline: 1.0832x; 1.0832x over previous
//
#include <hip/hip_runtime.h>
#include <hip/hip_bf16.h>

#define B_N 2048
#define E_N 64
#define D_N 512
#define O_N 512
#define NSL 4     // k-slices
#define KS  128   // k per slice
#define WLD 66    // ws row stride in ushorts (read: 4 g-groups land on disjoint bank octets)

typedef __bf16 bf16x8 __attribute__((ext_vector_type(8)));
typedef float  f32x4  __attribute__((ext_vector_type(4)));

__device__ __forceinline__ unsigned cvt2(float a, float b) {
  union { __hip_bfloat162 h; unsigned u; } c;
  c.h = __float22bfloat162_rn(make_float2(a, b));
  return c.u;   // low 16 = a, high 16 = b
}

// 8 blocks x 256: global-atomic bucketing (output is order-invariant).
__global__ __launch_bounds__(256)
void bucket_kernel(const int* __restrict__ opt, int* __restrict__ cnt,
                   int* __restrict__ list) {
  int b = blockIdx.x * 256 + threadIdx.x;
  int e = opt[b];
  int slot = atomicAdd(&cnt[e], 1);
  list[e * B_N + slot] = b;
}

// out[b][:] = bias[opt[b]][:]  (k-slice partials atomically accumulate on top)
__global__ __launch_bounds__(256)
void bias_init_kernel(const int* __restrict__ opt, const float* __restrict__ bias,
                      float* __restrict__ out) {
  int gid = blockIdx.x * 256 + threadIdx.x;   // 1024 blocks
  int b  = gid >> 7;
  int o4 = gid & 127;
  int e  = opt[b];
  reinterpret_cast<float4*>(out)[(size_t)b * 128 + o4] =
      reinterpret_cast<const float4*>(bias)[(size_t)e * 128 + o4];
}

// Max-TLP grouped GEMM: block = (expert e, 128-k slice s, 64-col tile q).
// 2048 blocks x 256 threads, 16.9 KB LDS, low VGPR -> 6-8 blocks/CU
// (24-32 waves/CU): latency hidden by wave count, fill-kernel style.
// Wave w owns cols q*64 + w*16 .. +15. B-frags in regs (read once from LDS);
// A-frags straight from global x (L2-hot, 4 MB); fp32 atomicAdd partials.
__global__ __launch_bounds__(256, 6)
void gemm_kernel(const float* __restrict__ x, const float* __restrict__ w,
                 const int* __restrict__ cnt, const int* __restrict__ list,
                 float* __restrict__ out) {
  __shared__ unsigned short ws[KS * WLD];   // 16896 B

  const int e    = blockIdx.x;
  const int s    = blockIdx.y;
  const int q    = blockIdx.z;
  const int t    = threadIdx.x;
  const int lane = t & 63;
  const int wave = t >> 6;
  const int n    = cnt[e];
  if (n == 0) return;

  const int m_in = lane & 15;
  const int g    = lane >> 4;
  const int* mylist = list + e * B_N;

  // ---- stage W tile: 128 k-rows x 64 cols (256 B contiguous per row) ----
  const float* wsl = w + (size_t)e * D_N * O_N + (size_t)s * KS * O_N + q * 64;
#pragma unroll
  for (int rnd = 0; rnd < 2; ++rnd) {
    float4 f[4];
#pragma unroll
    for (int i = 0; i < 4; ++i) {
      int idx = t + (rnd * 4 + i) * 256;   // 2048 float4 total
      int row = idx >> 4;                  // 16 float4 per k-row
      int c4  = idx & 15;
      f[i] = *reinterpret_cast<const float4*>(wsl + (size_t)row * O_N + c4 * 4);
    }
#pragma unroll
    for (int i = 0; i < 4; ++i) {
      int idx = t + (rnd * 4 + i) * 256;
      int row = idx >> 4;
      int c4  = idx & 15;
      *reinterpret_cast<uint2*>(&ws[row * WLD + c4 * 4]) =
          make_uint2(cvt2(f[i].x, f[i].y), cvt2(f[i].z, f[i].w));
    }
  }
  __syncthreads();     // the only barrier

  // ---- this wave's 4 B-fragments (16 cols x 128 k) -> registers ----
  union { unsigned short us[8]; bf16x8 v; } frag[4];
#pragma unroll
  for (int ks = 0; ks < 4; ++ks)
#pragma unroll
    for (int j = 0; j < 8; ++j)
      frag[ks].us[j] = ws[(ks * 32 + g * 8 + j) * WLD + wave * 16 + m_in];

  const float* xsl = x + (size_t)s * KS;
  const int ocol = q * 64 + wave * 16 + m_in;

  for (int m0 = 0; m0 < n; m0 += 16) {
    int sa = m0 + m_in;
    const float* xr = xsl + (size_t)mylist[sa < n ? sa : 0] * D_N + g * 8;

    f32x4 acc = {0.f, 0.f, 0.f, 0.f};
#pragma unroll
    for (int ks = 0; ks < 4; ++ks) {
      union { float4 q2[2]; float e8[8]; } xa;
      xa.q2[0] = *reinterpret_cast<const float4*>(xr + ks * 32);
      xa.q2[1] = *reinterpret_cast<const float4*>(xr + ks * 32 + 4);
      union { unsigned u[4]; bf16x8 v; } a;
#pragma unroll
      for (int p = 0; p < 4; ++p) a.u[p] = cvt2(xa.e8[2 * p], xa.e8[2 * p + 1]);
      acc = __builtin_amdgcn_mfma_f32_16x16x32_bf16(a.v, frag[ks].v, acc, 0, 0, 0);
    }

    // D layout (m89-verified): col = lane&15, row(slot) = g*4 + r
#pragma unroll
    for (int r = 0; r < 4; ++r) {
      int so = m0 + g * 4 + r;
      if (so < n)
        atomicAdd(out + (size_t)mylist[so] * O_N + ocol, acc[r]);
    }
  }
}

extern "C" void kernel_launch(void* const* d_in, const int* in_sizes, int n_in,
                              void* d_out, int out_size, void* d_ws, size_t ws_size,
                              hipStream_t stream) {
  const float* x      = (const float*)d_in[0];
  const int*   option = (const int*)d_in[1];
  const float* weight = (const float*)d_in[2];
  const float* bias   = (const float*)d_in[3];
  float* out = (float*)d_out;

  int* cnt  = (int*)d_ws;                    // 64 ints
  int* list = (int*)((char*)d_ws + 256);     // 64 * 2048 ints

  hipMemsetAsync(cnt, 0, E_N * sizeof(int), stream);
  bucket_kernel<<<B_N / 256, 256, 0, stream>>>(option, cnt, list);
  bias_init_kernel<<<(B_N * O_N / 4) / 256, 256, 0, stream>>>(option, bias, out);
  gemm_kernel<<<dim3(E_N, NSL, 8), 256, 0, stream>>>(x, weight, cnt, list, out);
}